// Round 7
// baseline (69.255 us; speedup 1.0000x reference)
//
#include <hip/hip_runtime.h>

#define EN 9
#define DD 64
#define SS 512
#define HH 1024
#define NOUT 1152  // EN*DD*2

typedef float f32x4 __attribute__((ext_vector_type(4)));

#define GPTR(p) ((const __attribute__((address_space(1))) void*)(p))
#define LPTR(p) ((__attribute__((address_space(3))) void*)(p))

__device__ inline int pk4_fp8(float a, float b, float c, float d) {
  int v = __builtin_amdgcn_cvt_pk_fp8_f32(a, b, 0, false);
  v = __builtin_amdgcn_cvt_pk_fp8_f32(c, d, v, true);
  return v;
}

// ---- prep: W -> Wf8 (e4m3, transposed, 8B-chunk XOR-swizzled),
//            X -> Xf8 (e4m3, 8B-chunk XOR-swizzled), rope tables ----
__global__ __launch_bounds__(256) void prep_kernel(
    const float* __restrict__ W, const float* __restrict__ X,
    unsigned char* __restrict__ Wf8, unsigned char* __restrict__ Xf8,
    float* __restrict__ ctab, float* __restrict__ stab) {
  if (blockIdx.x < 288u) {
    __shared__ float t[64][65];
    const int k0 = (blockIdx.x / 18) * 64;
    const int n0 = (blockIdx.x % 18) * 64;
    const int r = threadIdx.x >> 6;
    const int c = threadIdx.x & 63;
#pragma unroll
    for (int i = 0; i < 16; ++i) {
      const int kk = (i << 2) + r;
      t[kk][c] = W[(size_t)(k0 + kk) * NOUT + n0 + c];
    }
    __syncthreads();
#pragma unroll
    for (int i = 0; i < 2; ++i) {
      const int p = (i << 8) + threadIdx.x;  // 0..511
      const int n = p >> 3, cc = p & 7;
      const int kk = cc << 3;
      const int lo = pk4_fp8(t[kk][n], t[kk + 1][n], t[kk + 2][n], t[kk + 3][n]);
      const int hi =
          pk4_fp8(t[kk + 4][n], t[kk + 5][n], t[kk + 6][n], t[kk + 7][n]);
      const int gn = n0 + n;
      int2 v;
      v.x = lo;
      v.y = hi;
      *(int2*)(Wf8 + (size_t)gn * HH + k0 + ((cc ^ (gn & 7)) << 3)) = v;
    }
  } else if (blockIdx.x < 304u) {
    const int bt = blockIdx.x - 288;
#pragma unroll
    for (int j = 0; j < 4; ++j) {
      const int id = bt * 1024 + j * 256 + threadIdx.x;
      const int s = id >> 5, i = id & 31;
      const float freq = expf(-(float)(2 * i) * (9.210340371976184f / 64.0f));
      const float ang = (float)s * freq;
      ctab[id] = cosf(ang);
      stab[id] = sinf(ang);
    }
  } else {
    // X f32 -> fp8, 8-elem chunks; 1024 chunks per block
    const int bt = blockIdx.x - 304;
#pragma unroll
    for (int j = 0; j < 4; ++j) {
      const int C = bt * 1024 + (j << 8) + threadIdx.x;  // chunk id
      const int row = C >> 7, c = C & 127;               // chunk-in-row
      const float4 v0 = *(const float4*)(X + (size_t)C * 8);
      const float4 v1 = *(const float4*)(X + (size_t)C * 8 + 4);
      int2 v;
      v.x = pk4_fp8(v0.x, v0.y, v0.z, v0.w);
      v.y = pk4_fp8(v1.x, v1.y, v1.z, v1.w);
      *(int2*)(Xf8 + (size_t)row * HH + ((c >> 3) << 6) +
               (((c ^ row) & 7) << 3)) = v;
    }
  }
}

// ---- proj + rope (fp8 MFMA): 1-wave blocks, 64x64 tiles, barrier-free
//      counted-vmcnt pipeline. QK[b][h][{q,k}][s][64] fp8, pre-swizzled. ----
__global__ __launch_bounds__(64) void proj_rope_kernel(
    const unsigned char* __restrict__ Xf8, const unsigned char* __restrict__ Wf8,
    const float* __restrict__ bias, const float* __restrict__ ctab,
    const float* __restrict__ stab, unsigned char* __restrict__ QK) {
  // 2 bufs x (A 64x64 fp8 = 4KB | B 4KB) = 16KB
  __shared__ __align__(16) unsigned char sm[16384];
  const int lane = threadIdx.x;  // 0..63, one wave per block
  // XCD-chunked remap (8 XCDs x 288 blocks), n-fast inner order:
  // each XCD keeps 1MB of Xf8 rows + all of Wf8 (1.15MB) L2-resident.
  const int f = blockIdx.x;
  const int wkr = (f & 7) * 288 + (f >> 3);
  const int m0 = (wkr / 18) << 6;  // 128 m-tiles
  const int nt = wkr % 18;         // 18 n-tiles of 64
  const int n0 = nt << 6;
  const int hh = n0 >> 7;          // head
  const int tt = (n0 >> 6) & 1;    // 0=q, 1=k
  const float scale = (tt == 0) ? 0.125f : 1.0f;

  f32x4 acc[4][4];
#pragma unroll
  for (int i = 0; i < 4; ++i)
#pragma unroll
    for (int j = 0; j < 4; ++j) acc[i][j] = (f32x4){0.f, 0.f, 0.f, 0.f};

  const int sr = lane >> 2;          // staging row within 16-row group
  const int sg = (lane & 3) << 4;    // staging 16B granule offset

  // 8 global_load_lds per STAGE (4 A-rows-groups + 4 B): rows copied whole,
  // so prep's 8B-chunk XOR swizzle is preserved verbatim in LDS.
#define STAGE(BUF, KT)                                                      \
  {                                                                         \
    const int kt_ = (KT);                                                   \
    unsigned char* dst_ = sm + (BUF)*8192;                                  \
    _Pragma("unroll") for (int i = 0; i < 4; ++i) {                         \
      __builtin_amdgcn_global_load_lds(                                     \
          GPTR(Xf8 + (size_t)(m0 + (i << 4) + sr) * HH + kt_ + sg),         \
          LPTR(dst_ + (i << 10)), 16, 0, 0);                                \
    }                                                                       \
    _Pragma("unroll") for (int i = 0; i < 4; ++i) {                         \
      __builtin_amdgcn_global_load_lds(                                     \
          GPTR(Wf8 + (size_t)(n0 + (i << 4) + sr) * HH + kt_ + sg),         \
          LPTR(dst_ + 4096 + (i << 10)), 16, 0, 0);                         \
    }                                                                       \
  }

#define COMPUTE(BUF)                                                        \
  {                                                                         \
    const unsigned char* smc_ = sm + (BUF)*8192;                            \
    __builtin_amdgcn_s_setprio(1);                                          \
    _Pragma("unroll") for (int kb = 0; kb < 2; ++kb) {                      \
      long aL[4], bL[4];                                                    \
      const int c8 = (kb << 2) + (lane >> 4);                               \
      _Pragma("unroll") for (int i = 0; i < 4; ++i) {                       \
        const int ra = (i << 4) + (lane & 15);                              \
        aL[i] = *(const long*)(smc_ + (ra << 6) + (((c8 ^ ra) & 7) << 3));  \
        bL[i] = *(const long*)(smc_ + 4096 + (ra << 6) +                    \
                               (((c8 ^ ra) & 7) << 3));                     \
      }                                                                     \
      _Pragma("unroll") for (int mi = 0; mi < 4; ++mi)                      \
          _Pragma("unroll") for (int ni = 0; ni < 4; ++ni) acc[mi][ni] =    \
          __builtin_amdgcn_mfma_f32_16x16x32_fp8_fp8(aL[mi], bL[ni],        \
                                                     acc[mi][ni], 0, 0, 0); \
    }                                                                       \
    __builtin_amdgcn_s_setprio(0);                                          \
  }

  STAGE(0, 0)  // 8 loads in flight
#pragma unroll 1
  for (int t = 0; t < 15; ++t) {
    STAGE((t + 1) & 1, (t + 1) << 6)                  // +8 (16 outstanding)
    asm volatile("s_waitcnt vmcnt(8)" ::: "memory");  // tile t landed
    __builtin_amdgcn_sched_barrier(0);                // no ds_read hoisting
    COMPUTE(t & 1)
    // 1 wave per block: no cross-wave hazards, no barriers needed.
  }
  asm volatile("s_waitcnt vmcnt(0)" ::: "memory");
  __builtin_amdgcn_sched_barrier(0);
  COMPUTE(1)

  // ---- epilogue: LDS transpose -> in-thread rope pairs -> fp8 8B stores ----
  __syncthreads();  // 1-wave: cheap; forces lgkm drain before scr reuse
  float* scr = (float*)sm;  // 16 x 68 f32 = 4.4KB
  const int erow = lane >> 2;           // 0..15
  const int ecol = (lane & 3) << 4;     // 0,16,32,48
#pragma unroll
  for (int mi = 0; mi < 4; ++mi) {
#pragma unroll
    for (int ni = 0; ni < 4; ++ni) {
      const int col = (ni << 4) + (lane & 15);
#pragma unroll
      for (int r = 0; r < 4; ++r) {
        const int row = ((lane >> 4) << 2) + r;  // 0..15
        scr[row * 68 + col] = acc[mi][ni][r];
      }
    }
    __syncthreads();
    const int m = m0 + (mi << 4) + erow;
    const int s = m & (SS - 1);
    const int bb = m >> 9;
#pragma unroll
    for (int sl = 0; sl < 2; ++sl) {
      const int ncol = ecol + (sl << 3);  // d0, multiple of 8
      const int n = n0 + ncol;
      const float4 va = *(const float4*)&scr[erow * 68 + ncol];
      const float4 vb = *(const float4*)&scr[erow * 68 + ncol + 4];
      const float4 bia = *(const float4*)&bias[n];
      const float4 bib = *(const float4*)&bias[n + 4];
      const float4 cs = *(const float4*)&ctab[(s << 5) + (ncol >> 1)];
      const float4 sn = *(const float4*)&stab[(s << 5) + (ncol >> 1)];
      const float e0 = va.x + bia.x, o0 = va.y + bia.y;
      const float e1 = va.z + bia.z, o1 = va.w + bia.w;
      const float e2 = vb.x + bib.x, o2 = vb.y + bib.y;
      const float e3 = vb.z + bib.z, o3 = vb.w + bib.w;
      int2 ov;
      ov.x = pk4_fp8((e0 * cs.x - o0 * sn.x) * scale,
                     (o0 * cs.x + e0 * sn.x) * scale,
                     (e1 * cs.y - o1 * sn.y) * scale,
                     (o1 * cs.y + e1 * sn.y) * scale);
      ov.y = pk4_fp8((e2 * cs.z - o2 * sn.z) * scale,
                     (o2 * cs.z + e2 * sn.z) * scale,
                     (e3 * cs.w - o3 * sn.w) * scale,
                     (o3 * cs.w + e3 * sn.w) * scale);
      // pre-swizzled 8B chunk: chunk (ncol>>3) ^ (s&7)
      const int cswz = (((ncol >> 3) ^ (s & 7)) << 3);
      *(int2*)(QK + (((size_t)(bb * EN + hh) * 2 + tt) * SS + s) * DD + cswz) =
          ov;
    }
    __syncthreads();
  }
}

// ---- logits: per (b,h), 128x128 tiles of 512x512 (fp8 QK) ----
__global__ __launch_bounds__(256, 4) void logits_kernel(
    const unsigned char* __restrict__ QK, const float* __restrict__ pmask,
    float* __restrict__ out) {
  __shared__ __align__(16) unsigned char sm[16384];  // Q[128][64] | K[128][64]
  const int tid = threadIdx.x;
  const int lane = tid & 63;
  const int wid = tid >> 6;
  const int wr = wid >> 1, wc = wid & 1;
  const int f = blockIdx.x;
  const int wkr = (f & 7) * 288 + (f >> 3);
  const int bh = wkr >> 4;
  const int bb = bh / EN;
  const int tm = (wkr >> 2) & 3, tn = wkr & 3;
  const int mq0 = tm << 7, nk0 = tn << 7;
  const unsigned char* Qb = QK + (size_t)bh * 2 * SS * DD;
  const unsigned char* Kb = Qb + SS * DD;

  // stage 8KB Q + 8KB K; source is pre-swizzled, LDS linear.
#pragma unroll
  for (int it = 0; it < 2; ++it) {
    const int u = (it << 8) + tid;
    const int r = u >> 2, g = u & 3;
    __builtin_amdgcn_global_load_lds(
        GPTR(Qb + (size_t)(mq0 + r) * DD + (g << 4)),
        LPTR(sm + (((it << 8) + (wid << 6)) << 4)), 16, 0, 0);
    __builtin_amdgcn_global_load_lds(
        GPTR(Kb + (size_t)(nk0 + r) * DD + (g << 4)),
        LPTR(sm + 8192 + (((it << 8) + (wid << 6)) << 4)), 16, 0, 0);
  }
  __syncthreads();

  f32x4 acc[4][4];
#pragma unroll
  for (int i = 0; i < 4; ++i)
#pragma unroll
    for (int j = 0; j < 4; ++j) acc[i][j] = (f32x4){0.f, 0.f, 0.f, 0.f};

#pragma unroll
  for (int kb = 0; kb < 2; ++kb) {
    long aL[4], bL[4];
    const int c8 = (kb << 2) + (lane >> 4);
#pragma unroll
    for (int i = 0; i < 4; ++i) {
      const int ra = (wr << 6) + (i << 4) + (lane & 15);
      aL[i] = *(const long*)(sm + (ra << 6) + (((c8 ^ ra) & 7) << 3));
      const int rb = (wc << 6) + (i << 4) + (lane & 15);
      bL[i] = *(const long*)(sm + 8192 + (rb << 6) + (((c8 ^ rb) & 7) << 3));
    }
#pragma unroll
    for (int mi = 0; mi < 4; ++mi)
#pragma unroll
      for (int ni = 0; ni < 4; ++ni)
        acc[mi][ni] = __builtin_amdgcn_mfma_f32_16x16x32_fp8_fp8(
            aL[mi], bL[ni], acc[mi][ni], 0, 0, 0);
  }

#pragma unroll
  for (int mi = 0; mi < 4; ++mi) {
#pragma unroll
    for (int ni = 0; ni < 4; ++ni) {
      const int n = nk0 + (wc << 6) + (ni << 4) + (lane & 15);
      const float pd = pmask[bb * SS + n];
      const float sub = (1.0f - pd) * 1.25e11f;
#pragma unroll
      for (int r = 0; r < 4; ++r) {
        const int m = mq0 + (wr << 6) + (mi << 4) + ((lane >> 4) << 2) + r;
        float v = acc[mi][ni][r] * pd - sub;
        if (m > n) v -= 1.25e11f;
        out[((size_t)bh * SS + m) * SS + n] = v;
      }
    }
  }
}

extern "C" void kernel_launch(void* const* d_in, const int* in_sizes, int n_in,
                              void* d_out, int out_size, void* d_ws,
                              size_t ws_size, hipStream_t stream) {
  const float* X = (const float*)d_in[0];
  const float* pm = (const float*)d_in[1];
  const float* W = (const float*)d_in[2];
  const float* bias = (const float*)d_in[3];
  float* out = (float*)d_out;
  unsigned char* ws = (unsigned char*)d_ws;
  unsigned char* QK = ws;                 // 9,437,184 B (fp8)
  unsigned char* Wf8 = ws + 9437184;      // 1,179,648 B
  float* ctab = (float*)(ws + 10616832);  // 65,536 B
  float* stab = (float*)(ws + 10682368);  // 65,536 B
  unsigned char* Xf8 = ws + 10747904;     // 8,388,608 B

  prep_kernel<<<dim3(1328), dim3(256), 0, stream>>>(W, X, Wf8, Xf8, ctab, stab);
  proj_rope_kernel<<<dim3(2304), dim3(64), 0, stream>>>(Xf8, Wf8, bias, ctab,
                                                        stab, QK);
  logits_kernel<<<dim3(2304), dim3(256), 0, stream>>>(QK, pm, out);
}

// Round 8
// 62.234 us; speedup vs baseline: 1.1128x; 1.1128x over previous
//
#include <hip/hip_runtime.h>

#define EN 9
#define DD 64
#define SS 512
#define HH 1024
#define NOUT 1152  // EN*DD*2

typedef float f32x4 __attribute__((ext_vector_type(4)));

#define GPTR(p) ((const __attribute__((address_space(1))) void*)(p))
#define LPTR(p) ((__attribute__((address_space(3))) void*)(p))

__device__ inline int pk4_fp8(float a, float b, float c, float d) {
  int v = __builtin_amdgcn_cvt_pk_fp8_f32(a, b, 0, false);
  v = __builtin_amdgcn_cvt_pk_fp8_f32(c, d, v, true);
  return v;
}

// ---- prep: W -> Wkt[kt][1152][64B] (e4m3, 8B-chunk XOR-swizzled),
//            X -> Xkt[kt][8192][64B] (e4m3, 8B-chunk XOR-swizzled),
//            rope tables. k-tile-major => proj stages contiguous 8KB blocks.
__global__ __launch_bounds__(256) void prep_kernel(
    const float* __restrict__ W, const float* __restrict__ X,
    unsigned char* __restrict__ Wf8, unsigned char* __restrict__ Xf8,
    float* __restrict__ ctab, float* __restrict__ stab) {
  if (blockIdx.x < 288u) {
    __shared__ float t[64][65];
    const int k0 = (blockIdx.x / 18) * 64;
    const int n0 = (blockIdx.x % 18) * 64;
    const int r = threadIdx.x >> 6;
    const int c = threadIdx.x & 63;
#pragma unroll
    for (int i = 0; i < 16; ++i) {
      const int kk = (i << 2) + r;
      t[kk][c] = W[(size_t)(k0 + kk) * NOUT + n0 + c];
    }
    __syncthreads();
#pragma unroll
    for (int i = 0; i < 2; ++i) {
      const int p = (i << 8) + threadIdx.x;  // 0..511
      const int n = p >> 3, cc = p & 7;
      const int kk = cc << 3;
      const int lo = pk4_fp8(t[kk][n], t[kk + 1][n], t[kk + 2][n], t[kk + 3][n]);
      const int hi =
          pk4_fp8(t[kk + 4][n], t[kk + 5][n], t[kk + 6][n], t[kk + 7][n]);
      const int gn = n0 + n;
      int2 v;
      v.x = lo;
      v.y = hi;
      // W[kt=k0>>6][row=gn][chunk cc ^ (gn&7)]
      *(int2*)(Wf8 + ((size_t)(k0 >> 6) * NOUT + gn) * 64 +
               ((cc ^ (gn & 7)) << 3)) = v;
    }
  } else if (blockIdx.x < 304u) {
    const int bt = blockIdx.x - 288;
#pragma unroll
    for (int j = 0; j < 4; ++j) {
      const int id = bt * 1024 + j * 256 + threadIdx.x;
      const int s = id >> 5, i = id & 31;
      const float freq = expf(-(float)(2 * i) * (9.210340371976184f / 64.0f));
      const float ang = (float)s * freq;
      ctab[id] = cosf(ang);
      stab[id] = sinf(ang);
    }
  } else {
    // X f32 -> fp8, 8-elem chunks; 1024 chunks per block
    const int bt = blockIdx.x - 304;
#pragma unroll
    for (int j = 0; j < 4; ++j) {
      const int C = bt * 1024 + (j << 8) + threadIdx.x;  // chunk id
      const int row = C >> 7, c = C & 127;               // chunk-in-row
      const float4 v0 = *(const float4*)(X + (size_t)C * 8);
      const float4 v1 = *(const float4*)(X + (size_t)C * 8 + 4);
      int2 v;
      v.x = pk4_fp8(v0.x, v0.y, v0.z, v0.w);
      v.y = pk4_fp8(v1.x, v1.y, v1.z, v1.w);
      // X[kt=c>>3][row][chunk (c^row)&7]
      *(int2*)(Xf8 + ((size_t)(c >> 3) * 8192 + row) * 64 +
               (((c ^ row) & 7) << 3)) = v;
    }
  }
}

// ---- proj + rope (fp8 MFMA, 2-deep dbuf, k-tile-major staging):
//      QK[b][h][{q,k}][s][64] fp8, pre-swizzled. ----
__global__ __launch_bounds__(256, 4) void proj_rope_kernel(
    const unsigned char* __restrict__ Xf8, const unsigned char* __restrict__ Wf8,
    const float* __restrict__ bias, const float* __restrict__ ctab,
    const float* __restrict__ stab, unsigned char* __restrict__ QK) {
  // 2 bufs x (A 128x64 fp8 = 8KB | B 8KB) = 32KB; epilogue scratch reuses it
  __shared__ __align__(16) unsigned char sm[32768];
  const int tid = threadIdx.x;
  const int lane = tid & 63;
  const int wid = tid >> 6;
  const int wr = wid >> 1, wc = wid & 1;
  // XCD-chunked remap (8 XCDs x 72 blocks), n-fast inner order.
  const int f = blockIdx.x;
  const int wkr = (f & 7) * 72 + (f >> 3);
  const int m0 = (wkr / 9) << 7;
  const int n0 = (wkr % 9) << 7;

  f32x4 acc[4][4];
#pragma unroll
  for (int i = 0; i < 4; ++i)
#pragma unroll
    for (int j = 0; j < 4; ++j) acc[i][j] = (f32x4){0.f, 0.f, 0.f, 0.f};

  // staging: tile T's A slab = Xf8[(T*8192+m0)*64 .. +8KB) fully contiguous;
  // unit u = it*256+tid -> byte u*16 of the slab; LDS linear (image matches
  // the old row-major-swizzled one exactly, so COMPUTE is unchanged).
#define STAGE(BUF, T)                                                        \
  {                                                                          \
    const unsigned char* srcA_ = Xf8 + (((size_t)(T)*8192 + m0) << 6);       \
    const unsigned char* srcB_ = Wf8 + (((size_t)(T)*NOUT + n0) << 6);       \
    unsigned char* dst_ = sm + (BUF)*16384;                                  \
    _Pragma("unroll") for (int it = 0; it < 2; ++it) {                       \
      const int off_ = ((it << 8) + tid) << 4;                               \
      const int ldo_ = (((it << 8) + (wid << 6)) << 4);                      \
      __builtin_amdgcn_global_load_lds(GPTR(srcA_ + off_), LPTR(dst_ + ldo_), \
                                       16, 0, 0);                            \
      __builtin_amdgcn_global_load_lds(GPTR(srcB_ + off_),                   \
                                       LPTR(dst_ + 8192 + ldo_), 16, 0, 0);  \
    }                                                                        \
  }

#define COMPUTE(BUF)                                                         \
  {                                                                          \
    const unsigned char* smc_ = sm + (BUF)*16384;                            \
    __builtin_amdgcn_s_setprio(1);                                           \
    _Pragma("unroll") for (int kb = 0; kb < 2; ++kb) {                       \
      long aL[4], bL[4];                                                     \
      const int c8 = (kb << 2) + (lane >> 4);                                \
      _Pragma("unroll") for (int i = 0; i < 4; ++i) {                        \
        const int ra = (wr << 6) + (i << 4) + (lane & 15);                   \
        aL[i] = *(const long*)(smc_ + (ra << 6) + (((c8 ^ ra) & 7) << 3));   \
        const int rb = (wc << 6) + (i << 4) + (lane & 15);                   \
        bL[i] = *(const long*)(smc_ + 8192 + (rb << 6) +                     \
                               (((c8 ^ rb) & 7) << 3));                      \
      }                                                                      \
      _Pragma("unroll") for (int mi = 0; mi < 4; ++mi)                       \
          _Pragma("unroll") for (int ni = 0; ni < 4; ++ni) acc[mi][ni] =     \
          __builtin_amdgcn_mfma_f32_16x16x32_fp8_fp8(aL[mi], bL[ni],         \
                                                     acc[mi][ni], 0, 0, 0);  \
    }                                                                        \
    __builtin_amdgcn_s_setprio(0);                                           \
  }

  STAGE(0, 0)  // 4 loads in flight
#pragma unroll 1
  for (int t = 0; t < 15; ++t) {
    STAGE((t + 1) & 1, t + 1)                         // +4 (8 outstanding)
    asm volatile("s_waitcnt vmcnt(4)" ::: "memory");  // tile t landed
    __builtin_amdgcn_s_barrier();
    __builtin_amdgcn_sched_barrier(0);
    COMPUTE(t & 1)
    __builtin_amdgcn_sched_barrier(0);
    __builtin_amdgcn_s_barrier();  // reads of buf t done before overwrite
  }
  asm volatile("s_waitcnt vmcnt(0)" ::: "memory");
  __builtin_amdgcn_s_barrier();
  __builtin_amdgcn_sched_barrier(0);
  COMPUTE(1)

  // ---- epilogue: LDS transpose -> in-thread rope pairs -> fp8 8B stores ----
  // q-slice pre-scaled by 0.125 (folds the final /8 of the logits).
  __syncthreads();
  float* scr = (float*)sm;         // 32 x 132 f32 = 16.9KB (fits in 32KB)
  const int erow = tid >> 3;       // 0..31
  const int ec8 = (tid & 7) << 1;  // first of 2 col-octets
#pragma unroll
  for (int mi = 0; mi < 4; ++mi) {
#pragma unroll
    for (int ni = 0; ni < 4; ++ni) {
      const int col = (wc << 6) + (ni << 4) + (lane & 15);
#pragma unroll
      for (int r = 0; r < 4; ++r) {
        const int row = (wr << 4) + ((lane >> 4) << 2) + r;
        scr[row * 132 + col] = acc[mi][ni][r];
      }
    }
    __syncthreads();
    const int m = m0 + ((erow >> 4) << 6) + (mi << 4) + (erow & 15);
    const int s = m & (SS - 1);
    const int bb = m >> 9;
#pragma unroll
    for (int sl = 0; sl < 2; ++sl) {
      const int c8 = ec8 + sl;
      const int ncol = c8 << 3;  // 0..120
      const int n = n0 + ncol;
      const int h = n >> 7;
      const int t = (n >> 6) & 1;
      const int d0 = n & 63;  // multiple of 8
      const float scale = (t == 0) ? 0.125f : 1.0f;
      const float4 va = *(const float4*)&scr[erow * 132 + ncol];
      const float4 vb = *(const float4*)&scr[erow * 132 + ncol + 4];
      const float4 bia = *(const float4*)&bias[n];
      const float4 bib = *(const float4*)&bias[n + 4];
      const float4 cs = *(const float4*)&ctab[(s << 5) + (d0 >> 1)];
      const float4 sn = *(const float4*)&stab[(s << 5) + (d0 >> 1)];
      const float e0 = va.x + bia.x, o0 = va.y + bia.y;
      const float e1 = va.z + bia.z, o1 = va.w + bia.w;
      const float e2 = vb.x + bib.x, o2 = vb.y + bib.y;
      const float e3 = vb.z + bib.z, o3 = vb.w + bib.w;
      int2 ov;
      ov.x = pk4_fp8((e0 * cs.x - o0 * sn.x) * scale,
                     (o0 * cs.x + e0 * sn.x) * scale,
                     (e1 * cs.y - o1 * sn.y) * scale,
                     (o1 * cs.y + e1 * sn.y) * scale);
      ov.y = pk4_fp8((e2 * cs.z - o2 * sn.z) * scale,
                     (o2 * cs.z + e2 * sn.z) * scale,
                     (e3 * cs.w - o3 * sn.w) * scale,
                     (o3 * cs.w + e3 * sn.w) * scale);
      // pre-swizzled 8B chunk: chunk (d0>>3) ^ (s&7)
      const int cswz = (((d0 >> 3) ^ (s & 7)) << 3);
      *(int2*)(QK + (((size_t)(bb * EN + h) * 2 + t) * SS + s) * DD + cswz) =
          ov;
    }
    __syncthreads();
  }
}

// ---- logits: per (b,h), 128x128 tiles of 512x512 (fp8 QK) ----
__global__ __launch_bounds__(256, 4) void logits_kernel(
    const unsigned char* __restrict__ QK, const float* __restrict__ pmask,
    float* __restrict__ out) {
  __shared__ __align__(16) unsigned char sm[16384];  // Q[128][64] | K[128][64]
  const int tid = threadIdx.x;
  const int lane = tid & 63;
  const int wid = tid >> 6;
  const int wr = wid >> 1, wc = wid & 1;
  const int f = blockIdx.x;
  const int wkr = (f & 7) * 288 + (f >> 3);
  const int bh = wkr >> 4;
  const int bb = bh / EN;
  const int tm = (wkr >> 2) & 3, tn = wkr & 3;
  const int mq0 = tm << 7, nk0 = tn << 7;
  const unsigned char* Qb = QK + (size_t)bh * 2 * SS * DD;
  const unsigned char* Kb = Qb + SS * DD;

  // stage 8KB Q + 8KB K; source is pre-swizzled, LDS linear.
#pragma unroll
  for (int it = 0; it < 2; ++it) {
    const int u = (it << 8) + tid;
    const int r = u >> 2, g = u & 3;
    __builtin_amdgcn_global_load_lds(
        GPTR(Qb + (size_t)(mq0 + r) * DD + (g << 4)),
        LPTR(sm + (((it << 8) + (wid << 6)) << 4)), 16, 0, 0);
    __builtin_amdgcn_global_load_lds(
        GPTR(Kb + (size_t)(nk0 + r) * DD + (g << 4)),
        LPTR(sm + 8192 + (((it << 8) + (wid << 6)) << 4)), 16, 0, 0);
  }
  __syncthreads();

  f32x4 acc[4][4];
#pragma unroll
  for (int i = 0; i < 4; ++i)
#pragma unroll
    for (int j = 0; j < 4; ++j) acc[i][j] = (f32x4){0.f, 0.f, 0.f, 0.f};

#pragma unroll
  for (int kb = 0; kb < 2; ++kb) {
    long aL[4], bL[4];
    const int c8 = (kb << 2) + (lane >> 4);
#pragma unroll
    for (int i = 0; i < 4; ++i) {
      const int ra = (wr << 6) + (i << 4) + (lane & 15);
      aL[i] = *(const long*)(sm + (ra << 6) + (((c8 ^ ra) & 7) << 3));
      const int rb = (wc << 6) + (i << 4) + (lane & 15);
      bL[i] = *(const long*)(sm + 8192 + (rb << 6) + (((c8 ^ rb) & 7) << 3));
    }
#pragma unroll
    for (int mi = 0; mi < 4; ++mi)
#pragma unroll
      for (int ni = 0; ni < 4; ++ni)
        acc[mi][ni] = __builtin_amdgcn_mfma_f32_16x16x32_fp8_fp8(
            aL[mi], bL[ni], acc[mi][ni], 0, 0, 0);
  }

#pragma unroll
  for (int mi = 0; mi < 4; ++mi) {
#pragma unroll
    for (int ni = 0; ni < 4; ++ni) {
      const int n = nk0 + (wc << 6) + (ni << 4) + (lane & 15);
      const float pd = pmask[bb * SS + n];
      const float sub = (1.0f - pd) * 1.25e11f;
#pragma unroll
      for (int r = 0; r < 4; ++r) {
        const int m = mq0 + (wr << 6) + (mi << 4) + ((lane >> 4) << 2) + r;
        float v = acc[mi][ni][r] * pd - sub;
        if (m > n) v -= 1.25e11f;
        out[((size_t)bh * SS + m) * SS + n] = v;
      }
    }
  }
}

extern "C" void kernel_launch(void* const* d_in, const int* in_sizes, int n_in,
                              void* d_out, int out_size, void* d_ws,
                              size_t ws_size, hipStream_t stream) {
  const float* X = (const float*)d_in[0];
  const float* pm = (const float*)d_in[1];
  const float* W = (const float*)d_in[2];
  const float* bias = (const float*)d_in[3];
  float* out = (float*)d_out;
  unsigned char* ws = (unsigned char*)d_ws;
  unsigned char* QK = ws;                 // 9,437,184 B (fp8)
  unsigned char* Wf8 = ws + 9437184;      // 1,179,648 B (k-tile-major)
  float* ctab = (float*)(ws + 10616832);  // 65,536 B
  float* stab = (float*)(ws + 10682368);  // 65,536 B
  unsigned char* Xf8 = ws + 10747904;     // 8,388,608 B (k-tile-major)

  prep_kernel<<<dim3(1328), dim3(256), 0, stream>>>(W, X, Wf8, Xf8, ctab, stab);
  proj_rope_kernel<<<dim3(576), dim3(256), 0, stream>>>(Xf8, Wf8, bias, ctab,
                                                        stab, QK);
  logits_kernel<<<dim3(2304), dim3(256), 0, stream>>>(QK, pm, out);
}